// Round 1
// baseline (344.743 us; speedup 1.0000x reference)
//
#include <hip/hip_runtime.h>

// Problem constants (from reference)
#define B_   4
#define N_   8192
#define S_   2048
#define C1_  128
#define C2_  256
#define CIN_ 384
#define H_   256

// ---------------------------------------------------------------------------
// zero the stats region (sum1, sq1, scale1, shift1, sum2, sq2, scale2, shift2)
__global__ __launch_bounds__(256) void zero_stats_kernel(float* __restrict__ stats) {
  for (int i = threadIdx.x; i < 2048; i += 256) stats[i] = 0.f;
}

// ---------------------------------------------------------------------------
// 3-NN search: each block handles 64 query points; 4 waves each scan a quarter
// of the S=2048 candidates, partial top-3s merged in LDS by wave 0.
__global__ __launch_bounds__(256) void knn_kernel(const float* __restrict__ xyz1,
                                                  const float* __restrict__ xyz2,
                                                  int* __restrict__ idx,
                                                  float* __restrict__ wgt) {
  __shared__ float s2[S_ * 3];
  __shared__ float cd[64][4][3];
  __shared__ int   ci[64][4][3];
  const int b  = blockIdx.x >> 7;          // 128 chunks per batch
  const int n0 = (blockIdx.x & 127) << 6;  // 64 queries per block
  const int tid = threadIdx.x;
  for (int i = tid; i < S_ * 3; i += 256) s2[i] = xyz2[b * S_ * 3 + i];
  __syncthreads();
  const int q = tid >> 6;      // wave id -> candidate quarter (wave-uniform)
  const int ln = tid & 63;     // local query
  const int n = n0 + ln;
  const float px = xyz1[(b * N_ + n) * 3 + 0];
  const float py = xyz1[(b * N_ + n) * 3 + 1];
  const float pz = xyz1[(b * N_ + n) * 3 + 2];
  float d0 = 1e30f, d1 = 1e30f, d2 = 1e30f;
  int j0 = 0, j1 = 0, j2 = 0;
  const int jend = (q + 1) * 512;
  for (int j = q * 512; j < jend; ++j) {
    float dx = px - s2[3 * j];
    float dy = py - s2[3 * j + 1];
    float dz = pz - s2[3 * j + 2];
    float d = fmaf(dx, dx, fmaf(dy, dy, dz * dz));
    if (d < d2) {
      if (d < d1) {
        d2 = d1; j2 = j1;
        if (d < d0) { d1 = d0; j1 = j0; d0 = d; j0 = j; }
        else        { d1 = d;  j1 = j; }
      } else { d2 = d; j2 = j; }
    }
  }
  cd[ln][q][0] = d0; cd[ln][q][1] = d1; cd[ln][q][2] = d2;
  ci[ln][q][0] = j0; ci[ln][q][1] = j1; ci[ln][q][2] = j2;
  __syncthreads();
  if (tid < 64) {
    float e0 = 1e30f, e1 = 1e30f, e2 = 1e30f;
    int k0 = 0, k1 = 0, k2 = 0;
    // insert in ascending-quarter order => ties keep lowest j (matches top_k)
    for (int qq = 0; qq < 4; ++qq)
      for (int kk = 0; kk < 3; ++kk) {
        float d = cd[tid][qq][kk];
        int jj = ci[tid][qq][kk];
        if (d < e2) {
          if (d < e1) {
            e2 = e1; k2 = k1;
            if (d < e0) { e1 = e0; k1 = k0; e0 = d; k0 = jj; }
            else        { e1 = d;  k1 = jj; }
          } else { e2 = d; k2 = jj; }
        }
      }
    float r0 = 1.f / (e0 + 1e-8f);
    float r1 = 1.f / (e1 + 1e-8f);
    float r2 = 1.f / (e2 + 1e-8f);
    float rs = 1.f / (r0 + r1 + r2);
    int base = (b * N_ + n0 + tid) * 3;
    idx[base] = k0; idx[base + 1] = k1; idx[base + 2] = k2;
    wgt[base] = r0 * rs; wgt[base + 1] = r1 * rs; wgt[base + 2] = r2 * rs;
  }
}

// ---------------------------------------------------------------------------
// copy points1 -> X channels [0,128)
__global__ __launch_bounds__(256) void copy_p1_kernel(const float* __restrict__ p1,
                                                      float* __restrict__ X) {
  int id = blockIdx.x * 256 + threadIdx.x;   // float4 id, total 1048576
  int b = id >> 18;                          // / (128*8192/4)
  int r = id & 262143;
  ((float4*)X)[(size_t)b * 786432 + r] = ((const float4*)p1)[id];
}

// ---------------------------------------------------------------------------
// interpolate points2 -> X channels [128,384). Block = (b, 4 channels);
// the 4 points2 rows (8 KB each) staged in LDS, gathers hit LDS.
__global__ __launch_bounds__(256) void interp_kernel(const float* __restrict__ p2,
                                                     const int* __restrict__ idx,
                                                     const float* __restrict__ wgt,
                                                     float* __restrict__ X) {
  __shared__ float rows[4][S_];
  const int b = blockIdx.x >> 6;
  const int cg = blockIdx.x & 63;
  const int tid = threadIdx.x;
  for (int i = tid; i < 4 * S_; i += 256)
    rows[i >> 11][i & (S_ - 1)] =
        p2[((size_t)b * C2_ + cg * 4 + (i >> 11)) * S_ + (i & (S_ - 1))];
  __syncthreads();
  for (int n = tid; n < N_; n += 256) {
    int base = (b * N_ + n) * 3;
    int i0 = idx[base], i1 = idx[base + 1], i2 = idx[base + 2];
    float w0 = wgt[base], w1 = wgt[base + 1], w2 = wgt[base + 2];
#pragma unroll
    for (int cc = 0; cc < 4; ++cc) {
      float v = w0 * rows[cc][i0] + w1 * rows[cc][i1] + w2 * rows[cc][i2];
      X[((size_t)b * CIN_ + C1_ + cg * 4 + cc) * N_ + n] = v;
    }
  }
}

// ---------------------------------------------------------------------------
// fp32 GEMM: C[b,o,n] = sum_k W[o,k]*Bin[b,k,n] + bias[o]
// Tile 128x128, BK=16, 256 threads, 8x8 micro-tile.
// FUSE: apply h = relu(bnscale[k]*v + bnshift[k]) to the B-operand on load.
// Epilogue accumulates per-channel sum / sum-of-squares for BatchNorm stats.
template <int K, bool FUSE>
__global__ __launch_bounds__(256, 2) void gemm_kernel(
    const float* __restrict__ W, const float* __restrict__ Bin,
    const float* __restrict__ bias,
    const float* __restrict__ bnscale, const float* __restrict__ bnshift,
    float* __restrict__ Cout, float* __restrict__ osum, float* __restrict__ osq) {
  __shared__ float As[16][128];  // [k][o]
  __shared__ float Bs[16][128];  // [k][n]
  const int tid = threadIdx.x;
  const int tx = tid & 15, ty = tid >> 4;
  const int nBase = blockIdx.x * 128;
  const int oBase = blockIdx.y * 128;
  const int b = blockIdx.z;

  float acc[8][8];
#pragma unroll
  for (int i = 0; i < 8; ++i)
#pragma unroll
    for (int j = 0; j < 8; ++j) acc[i][j] = 0.f;

  const int aRow = tid >> 1;           // 0..127
  const int aK = (tid & 1) * 8;        // 0 or 8
  const float* Ap = W + (size_t)(oBase + aRow) * K + aK;
  const int bK = tid >> 4;             // 0..15
  const int bN = (tid & 15) * 8;
  const float* Bp = Bin + ((size_t)b * K + bK) * N_ + nBase + bN;

  for (int k0 = 0; k0 < K; k0 += 16) {
    float4 a0 = *(const float4*)(Ap + k0);
    float4 a1 = *(const float4*)(Ap + k0 + 4);
    float4 v0 = *(const float4*)(Bp + (size_t)k0 * N_);
    float4 v1 = *(const float4*)(Bp + (size_t)k0 * N_ + 4);
    if (FUSE) {
      float sc = bnscale[k0 + bK], sh = bnshift[k0 + bK];
      v0.x = fmaxf(fmaf(v0.x, sc, sh), 0.f);
      v0.y = fmaxf(fmaf(v0.y, sc, sh), 0.f);
      v0.z = fmaxf(fmaf(v0.z, sc, sh), 0.f);
      v0.w = fmaxf(fmaf(v0.w, sc, sh), 0.f);
      v1.x = fmaxf(fmaf(v1.x, sc, sh), 0.f);
      v1.y = fmaxf(fmaf(v1.y, sc, sh), 0.f);
      v1.z = fmaxf(fmaf(v1.z, sc, sh), 0.f);
      v1.w = fmaxf(fmaf(v1.w, sc, sh), 0.f);
    }
    As[aK + 0][aRow] = a0.x; As[aK + 1][aRow] = a0.y;
    As[aK + 2][aRow] = a0.z; As[aK + 3][aRow] = a0.w;
    As[aK + 4][aRow] = a1.x; As[aK + 5][aRow] = a1.y;
    As[aK + 6][aRow] = a1.z; As[aK + 7][aRow] = a1.w;
    *(float4*)&Bs[bK][bN] = v0;
    *(float4*)&Bs[bK][bN + 4] = v1;
    __syncthreads();
#pragma unroll
    for (int k = 0; k < 16; ++k) {
      float4 x0 = *(const float4*)&As[k][ty * 8];
      float4 x1 = *(const float4*)&As[k][ty * 8 + 4];
      float4 y0 = *(const float4*)&Bs[k][tx * 8];
      float4 y1 = *(const float4*)&Bs[k][tx * 8 + 4];
      float av[8] = {x0.x, x0.y, x0.z, x0.w, x1.x, x1.y, x1.z, x1.w};
      float bv[8] = {y0.x, y0.y, y0.z, y0.w, y1.x, y1.y, y1.z, y1.w};
#pragma unroll
      for (int i = 0; i < 8; ++i)
#pragma unroll
        for (int j = 0; j < 8; ++j) acc[i][j] = fmaf(av[i], bv[j], acc[i][j]);
    }
    __syncthreads();
  }

  // epilogue: bias, store, per-channel stats
  float rs[8], rq[8];
#pragma unroll
  for (int r = 0; r < 8; ++r) {
    int o = oBase + ty * 8 + r;
    float bv = bias[o];
    float s = 0.f, qq = 0.f;
    float vv[8];
#pragma unroll
    for (int j = 0; j < 8; ++j) {
      float v = acc[r][j] + bv;
      vv[j] = v;
      s += v;
      qq = fmaf(v, v, qq);
    }
    float4* cp = (float4*)(Cout + ((size_t)b * H_ + o) * N_ + nBase + tx * 8);
    cp[0] = make_float4(vv[0], vv[1], vv[2], vv[3]);
    cp[1] = make_float4(vv[4], vv[5], vv[6], vv[7]);
    rs[r] = s; rq[r] = qq;
  }
  float* sred = &As[0][0];  // 2048 floats, reuse staging LDS
#pragma unroll
  for (int r = 0; r < 8; ++r) sred[(ty * 8 + r) * 16 + tx] = rs[r];
  __syncthreads();
  if (tid < 128) {
    float s = 0.f;
#pragma unroll
    for (int t = 0; t < 16; ++t) s += sred[tid * 16 + t];
    atomicAdd(&osum[oBase + tid], s);
  }
  __syncthreads();
#pragma unroll
  for (int r = 0; r < 8; ++r) sred[(ty * 8 + r) * 16 + tx] = rq[r];
  __syncthreads();
  if (tid < 128) {
    float s = 0.f;
#pragma unroll
    for (int t = 0; t < 16; ++t) s += sred[tid * 16 + t];
    atomicAdd(&osq[oBase + tid], s);
  }
}

// ---------------------------------------------------------------------------
__global__ void finalize_bn_kernel(const float* __restrict__ sum,
                                   const float* __restrict__ sq,
                                   const float* __restrict__ gamma,
                                   const float* __restrict__ beta,
                                   float* __restrict__ scale,
                                   float* __restrict__ shift) {
  int o = threadIdx.x;
  if (o < 256) {
    const float inv_n = 1.f / 32768.f;  // B*N
    float mean = sum[o] * inv_n;
    float var = sq[o] * inv_n - mean * mean;
    float s = gamma[o] * rsqrtf(var + 1e-5f);
    scale[o] = s;
    shift[o] = fmaf(-mean, s, beta[o]);
  }
}

// in-place BN + ReLU on the final output
__global__ __launch_bounds__(256) void bn_apply_kernel(float* __restrict__ io,
                                                       const float* __restrict__ scale,
                                                       const float* __restrict__ shift) {
  int id = blockIdx.x * 256 + threadIdx.x;  // float4 id, total 2097152
  int row = id >> 11;                       // N/4 = 2048 float4 per row
  int o = row & 255;
  float sc = scale[o], sh = shift[o];
  float4 v = ((float4*)io)[id];
  v.x = fmaxf(fmaf(v.x, sc, sh), 0.f);
  v.y = fmaxf(fmaf(v.y, sc, sh), 0.f);
  v.z = fmaxf(fmaf(v.z, sc, sh), 0.f);
  v.w = fmaxf(fmaf(v.w, sc, sh), 0.f);
  ((float4*)io)[id] = v;
}

// ---------------------------------------------------------------------------
extern "C" void kernel_launch(void* const* d_in, const int* in_sizes, int n_in,
                              void* d_out, int out_size, void* d_ws, size_t ws_size,
                              hipStream_t stream) {
  const float* xyz1 = (const float*)d_in[0];
  const float* xyz2 = (const float*)d_in[1];
  const float* p1   = (const float*)d_in[2];
  const float* p2   = (const float*)d_in[3];
  const float* W1   = (const float*)d_in[4];
  const float* b1   = (const float*)d_in[5];
  const float* g1   = (const float*)d_in[6];
  const float* be1  = (const float*)d_in[7];
  const float* W2   = (const float*)d_in[8];
  const float* b2   = (const float*)d_in[9];
  const float* g2   = (const float*)d_in[10];
  const float* be2  = (const float*)d_in[11];
  float* out = (float*)d_out;

  float* ws = (float*)d_ws;
  float* X    = ws;                                    // [B,384,N]  12.58M floats
  float* Y1   = X + (size_t)B_ * CIN_ * N_;            // [B,256,N]   8.39M floats
  float* wgt  = Y1 + (size_t)B_ * H_ * N_;             // [B,N,3]
  float* stats = wgt + (size_t)B_ * N_ * 3;            // 2048 floats
  int*   idxb = (int*)(stats + 2048);                  // [B,N,3] ints
  float* sum1 = stats,        *sq1 = stats + 256;
  float* scale1 = stats + 512, *shift1 = stats + 768;
  float* sum2 = stats + 1024, *sq2 = stats + 1280;
  float* scale2 = stats + 1536, *shift2 = stats + 1792;

  zero_stats_kernel<<<1, 256, 0, stream>>>(stats);
  knn_kernel<<<512, 256, 0, stream>>>(xyz1, xyz2, idxb, wgt);
  copy_p1_kernel<<<4096, 256, 0, stream>>>(p1, X);
  interp_kernel<<<256, 256, 0, stream>>>(p2, idxb, wgt, X);

  dim3 gg(64, 2, 4);
  gemm_kernel<CIN_, false><<<gg, 256, 0, stream>>>(W1, X, b1, nullptr, nullptr,
                                                   Y1, sum1, sq1);
  finalize_bn_kernel<<<1, 256, 0, stream>>>(sum1, sq1, g1, be1, scale1, shift1);
  gemm_kernel<H_, true><<<gg, 256, 0, stream>>>(W2, Y1, b2, scale1, shift1,
                                                out, sum2, sq2);
  finalize_bn_kernel<<<1, 256, 0, stream>>>(sum2, sq2, g2, be2, scale2, shift2);
  bn_apply_kernel<<<8192, 256, 0, stream>>>(out, scale2, shift2);
}